// Round 1
// baseline (218.879 us; speedup 1.0000x reference)
//
#include <hip/hip_runtime.h>
#include <cstdint>

// ---------------- compile-time DCT matrix + grade filter ----------------
constexpr double kPI = 3.14159265358979323846264338327950288;

constexpr double cos_poly(double x) {            // |x| <= pi/2, Taylor
    double x2 = x * x, term = 1.0, sum = 1.0;
    for (int n = 1; n <= 13; ++n) { term *= -x2 / double((2 * n - 1) * (2 * n)); sum += term; }
    return sum;
}
constexpr double cos_idx(int a) {                // cos(a*pi/64), a mod 128
    a &= 127;
    if (a <= 32)  return  cos_poly(a * kPI / 64.0);
    if (a <= 64)  return -cos_poly((64 - a) * kPI / 64.0);
    if (a <= 96)  return -cos_poly((a - 64) * kPI / 64.0);
    return cos_poly((128 - a) * kPI / 64.0);
}
constexpr double csqrt(double v) {
    double x = 1.0;
    for (int i = 0; i < 60; ++i) x = 0.5 * (x + v / x);
    return x;
}
struct DTab { float d[1024]; };
constexpr DTab make_D() {
    DTab t{};
    const double s0 = csqrt(1.0 / 32.0);
    for (int i = 0; i < 32; ++i) {
        double sc = (i == 0) ? s0 : 0.25;            // sqrt(2/32) = 0.25 exactly
        for (int j = 0; j < 32; ++j) {
            int a = ((2 * j + 1) * i) & 127;         // (j+0.5)*pi*i/32 == a*pi/64
            t.d[i * 32 + j] = (float)(sc * cos_idx(a));
        }
    }
    return t;
}
struct FTab { float f[64]; };
constexpr FTab make_F() {                            // f(s) = sum_g [s in band g] 2^g/n_g
    FTab t{};
    const int lo[6] = {0, 11, 22, 32, 43, 54};
    const int hi[6] = {10, 21, 32, 42, 53, 62};      // s=32 is in bands 2 AND 3 (fp64 boundary = 32.0)
    const int n [6] = {66, 187, 306, 286, 165, 45};
    for (int s = 0; s < 64; ++s) {
        double acc = 0.0, w = 1.0;
        for (int g = 0; g < 6; ++g) { if (s >= lo[g] && s <= hi[g]) acc += w / double(n[g]); w *= 2.0; }
        t.f[s] = (float)acc;
    }
    return t;
}
__constant__ DTab cD = make_D();
__constant__ FTab cF = make_F();

#define NP 15376   // 16 * 961 patches
#define LPB 961    // 31*31 patches per batch image

// ---------------- kernel 1: per-patch grade ----------------
// one 32-lane group per patch; 8 groups / 256-thread block; channels looped.
__global__ __launch_bounds__(256) void k_grade(const float* __restrict__ x,
                                               float* __restrict__ partial) {
    __shared__ float sT[8][32 * 33];   // per-group T transpose buffer, +1 pad: conflict-free
    __shared__ float sF[64];
    const int tid  = threadIdx.x;
    const int g    = tid >> 5;
    const int lane = tid & 31;
    if (tid < 64) sF[tid] = cF.f[tid];

    const int task = blockIdx.x * 8 + g;             // patch id, grid is exact (1922*8 = 15376)
    const int b  = task / LPB;
    const int l  = task - b * LPB;
    const int ph = l / 31, pw = l - ph * 31;
    const float* xb = x + (b * 3) * 262144 + (ph * 16) * 512 + pw * 16;
    float* myT = sT[g];
    float gsum = 0.0f;

    __syncthreads();
    for (int c = 0; c < 3; ++c) {
        const float* xc = xb + c * 262144;
        float p[32];
        #pragma unroll
        for (int k = 0; k < 32; ++k) p[k] = xc[k * 512 + lane];   // coalesced 128B rows

        // T[i][lane] = sum_k D[i][k] * P[k][lane];  D via uniform-index s_load (SGPR operand)
        #pragma unroll 2
        for (int i = 0; i < 32; ++i) {
            float acc = 0.0f;
            #pragma unroll
            for (int k = 0; k < 32; ++k) acc = fmaf(cD.d[i * 32 + k], p[k], acc);
            myT[i * 33 + lane] = acc;
        }
        __syncthreads();

        // row r = lane of T, then Z[r][j] = sum_k T[r][k] * D[j][k]; fuse log+weight
        float t[32];
        #pragma unroll
        for (int k = 0; k < 32; ++k) t[k] = myT[lane * 33 + k];
        #pragma unroll 2
        for (int j = 0; j < 32; ++j) {
            float acc = 0.0f;
            #pragma unroll
            for (int k = 0; k < 32; ++k) acc = fmaf(t[k], cD.d[j * 32 + k], acc);
            float lx = __logf(fabsf(acc) + 1.0f);
            gsum = fmaf(lx, sF[lane + j], gsum);     // s = row + col, consecutive across lanes
        }
        __syncthreads();                             // protect sT reuse next channel
    }
    #pragma unroll
    for (int off = 16; off > 0; off >>= 1) gsum += __shfl_down(gsum, off, 32);
    if (lane == 0) partial[task] = gsum;
}

// ---------------- kernel 2: top-2 / bottom-2 per batch ----------------
// key = (grade_bits << 32) | idx ; grades >= 0 so float bits are monotone.
// min key => smallest grade, smallest idx (matches stable argsort idx[0]/idx[1]);
// max key => largest grade, LARGEST idx (matches idx[-1]/idx[-2]).
__global__ __launch_bounds__(256) void k_select(const float* __restrict__ partial,
                                                int* __restrict__ sel) {
    __shared__ unsigned long long smx1[256], smx2[256], smn1[256], smn2[256];
    const int b = blockIdx.x, tid = threadIdx.x;
    unsigned long long mx1 = 0, mx2 = 0, mn1 = ~0ULL, mn2 = ~0ULL;
    for (int l = tid; l < LPB; l += 256) {           // every thread sees >= 3 entries
        unsigned int bits = __float_as_uint(partial[b * LPB + l]);
        unsigned long long k = ((unsigned long long)bits << 32) | (unsigned int)l;
        if (k > mx1) { mx2 = mx1; mx1 = k; } else if (k > mx2) { mx2 = k; }
        if (k < mn1) { mn2 = mn1; mn1 = k; } else if (k < mn2) { mn2 = k; }
    }
    smx1[tid] = mx1; smx2[tid] = mx2; smn1[tid] = mn1; smn2[tid] = mn2;
    for (int off = 128; off > 0; off >>= 1) {
        __syncthreads();
        if (tid < off) {
            unsigned long long a1 = smx1[tid], a2 = smx2[tid], b1 = smx1[tid + off], b2 = smx2[tid + off];
            unsigned long long lo = a1 < b1 ? a1 : b1, hi = a1 < b1 ? b1 : a1;
            unsigned long long c2 = a2 > b2 ? a2 : b2;
            smx1[tid] = hi; smx2[tid] = lo > c2 ? lo : c2;
            a1 = smn1[tid]; a2 = smn2[tid]; b1 = smn1[tid + off]; b2 = smn2[tid + off];
            lo = a1 < b1 ? a1 : b1; hi = a1 < b1 ? b1 : a1;
            c2 = a2 < b2 ? a2 : b2;
            smn1[tid] = lo; smn2[tid] = hi < c2 ? hi : c2;
        }
    }
    __syncthreads();
    if (tid == 0) {
        sel[b * 4 + 0] = (int)(smn1[0] & 0xffffffffu);  // x_minmin
        sel[b * 4 + 1] = (int)(smx1[0] & 0xffffffffu);  // x_maxmax
        sel[b * 4 + 2] = (int)(smn2[0] & 0xffffffffu);  // x_minmin1
        sel[b * 4 + 3] = (int)(smx2[0] & 0xffffffffu);  // x_maxmax1
    }
}

// ---------------- kernel 3: gather selected raw patches ----------------
// level_y == patches exactly (LEVEL_FILT is all-ones, D orthonormal).
__global__ __launch_bounds__(256) void k_gather(const float* __restrict__ x,
                                                const int* __restrict__ sel,
                                                float* __restrict__ out) {
    const int e = blockIdx.x * 256 + threadIdx.x;    // 768*256 = 196608 exact
    const int o  = e / 49152;          // which of the 4 outputs
    const int r  = e - o * 49152;
    const int b  = r / 3072;
    const int r2 = r - b * 3072;
    const int c  = r2 >> 10;
    const int p  = r2 & 1023;
    const int i  = p >> 5, j = p & 31;
    const int l  = sel[b * 4 + o];
    const int r0 = (l / 31) * 16, c0 = (l - (l / 31) * 31) * 16;
    out[e] = x[((b * 3 + c) * 512 + r0 + i) * 512 + c0 + j];
}

extern "C" void kernel_launch(void* const* d_in, const int* in_sizes, int n_in,
                              void* d_out, int out_size, void* d_ws, size_t ws_size,
                              hipStream_t stream) {
    const float* x = (const float*)d_in[0];
    float* out     = (float*)d_out;
    float* partial = (float*)d_ws;                   // NP floats
    int*   sel     = (int*)d_ws + 16384;             // 64 ints at byte offset 64 KiB
    k_grade <<<NP / 8, 256, 0, stream>>>(x, partial);
    k_select<<<16,     256, 0, stream>>>(partial, sel);
    k_gather<<<768,    256, 0, stream>>>(x, sel, out);
}

// Round 3
// 179.274 us; speedup vs baseline: 1.2209x; 1.2209x over previous
//
#include <hip/hip_runtime.h>
#include <cstdint>

// ---------------- compile-time DCT tables (butterfly-packed) ----------------
constexpr double kPI = 3.14159265358979323846264338327950288;
constexpr double cos_poly(double x) {            // |x| <= pi/2, Taylor
    double x2 = x * x, term = 1.0, sum = 1.0;
    for (int n = 1; n <= 13; ++n) { term *= -x2 / double((2 * n - 1) * (2 * n)); sum += term; }
    return sum;
}
constexpr double cos_idx(int a) {                // cos(a*pi/64), a mod 128
    a &= 127;
    if (a <= 32)  return  cos_poly(a * kPI / 64.0);
    if (a <= 64)  return -cos_poly((64 - a) * kPI / 64.0);
    if (a <= 96)  return -cos_poly((a - 64) * kPI / 64.0);
    return cos_poly((128 - a) * kPI / 64.0);
}
constexpr double csqrt(double v) {
    double x = 1.0;
    for (int i = 0; i < 60; ++i) x = 0.5 * (x + v / x);
    return x;
}
constexpr float Dij(int i, int j) {              // D[i][j], 32-point DCT-II
    double sc = (i == 0) ? csqrt(1.0 / 32.0) : 0.25;   // sqrt(2/32) == 0.25 exactly
    int a = ((2 * j + 1) * i) & 127;
    return (float)(sc * cos_idx(a));
}
// D[i][31-k] = (-1)^i D[i][k]  (stage 1);  even rows fold again (stage 2).
struct OddT { float d[256]; };                   // Odd[m][k] = D[2m+1][k], k<16
constexpr OddT make_odd() { OddT t{}; for (int m = 0; m < 16; ++m) for (int k = 0; k < 16; ++k) t.d[m*16+k] = Dij(2*m+1, k); return t; }
struct E8T { float d[64]; };
constexpr E8T make_e0() { E8T t{}; for (int m = 0; m < 8; ++m) for (int k = 0; k < 8; ++k) t.d[m*8+k] = Dij(4*m,   k); return t; }
constexpr E8T make_e2() { E8T t{}; for (int m = 0; m < 8; ++m) for (int k = 0; k < 8; ++k) t.d[m*8+k] = Dij(4*m+2, k); return t; }
struct FTab { float f[64]; };
constexpr FTab make_F() {                        // f(s) = sum_g [s in band g] 2^g/n_g
    FTab t{};
    const int lo[6] = {0, 11, 22, 32, 43, 54};
    const int hi[6] = {10, 21, 32, 42, 53, 62};  // s=32 in bands 2 AND 3 (fp64 boundary = 32.0)
    const int n [6] = {66, 187, 306, 286, 165, 45};
    for (int s = 0; s < 64; ++s) {
        double acc = 0.0, w = 1.0;
        for (int g = 0; g < 6; ++g) { if (s >= lo[g] && s <= hi[g]) acc += w / double(n[g]); w *= 2.0; }
        t.f[s] = (float)acc;
    }
    return t;
}
__constant__ OddT cOdd = make_odd();
__constant__ E8T  cE0  = make_e0();
__constant__ E8T  cE2  = make_e2();
__constant__ FTab cF   = make_F();

#define NP  15376   // 16 * 961 patches
#define LPB 961     // 31*31 patches per batch image

// 32-point DCT-II with 2 butterfly stages: 384 FMA + 48 add (vs 1024 FMA).
template <typename EMIT>
__device__ __forceinline__ void dct32(const float* __restrict__ v, EMIT&& emit) {
    float e[16], o[16];
    #pragma unroll
    for (int k = 0; k < 16; ++k) { e[k] = v[k] + v[31-k]; o[k] = v[k] - v[31-k]; }
    float ee[8], eo[8];
    #pragma unroll
    for (int k = 0; k < 8; ++k)  { ee[k] = e[k] + e[15-k]; eo[k] = e[k] - e[15-k]; }
    #pragma unroll
    for (int m = 0; m < 16; m += 2) {            // odd outputs, 2 chains for ILP
        float a = 0.f, b = 0.f;
        #pragma unroll
        for (int k = 0; k < 16; ++k) {
            a = fmaf(cOdd.d[m*16+k],     o[k], a);
            b = fmaf(cOdd.d[(m+1)*16+k], o[k], b);
        }
        emit(2*m+1, a); emit(2*m+3, b);
    }
    #pragma unroll
    for (int m = 0; m < 8; m += 2) {             // even outputs, 4 chains
        float a0 = 0.f, a2 = 0.f, b0 = 0.f, b2 = 0.f;
        #pragma unroll
        for (int k = 0; k < 8; ++k) {
            a0 = fmaf(cE0.d[m*8+k],     ee[k], a0);
            a2 = fmaf(cE2.d[m*8+k],     eo[k], a2);
            b0 = fmaf(cE0.d[(m+1)*8+k], ee[k], b0);
            b2 = fmaf(cE2.d[(m+1)*8+k], eo[k], b2);
        }
        emit(4*m, a0); emit(4*m+2, a2); emit(4*m+4, b0); emit(4*m+6, b2);
    }
}

// ---------------- kernel 1: per-patch grade ----------------
// 64-thread (single-wave) blocks: s_barrier lowers to free wave_barrier,
// LDS 8.7 KB -> 16 waves/CU.  Lane = row for pass 1 (contiguous float4 row
// loads), one 33-stride LDS transpose, lane = column for pass 2.
// LDS map: S[a*33 + b] = U[b][a]  (write S[j*33+lane]=U[lane][j];
//          read  u[j] = S[lane*33+j] = U[j][lane] — the transpose).
__global__ __launch_bounds__(64) void k_grade(const float* __restrict__ x,
                                              float* __restrict__ partial) {
    __shared__ float sS[2][32 * 33];             // U buffer per 32-lane group
    __shared__ float sF[64];
    const int tid = threadIdx.x, g = tid >> 5, lane = tid & 31;
    sF[tid] = cF.f[tid];

    const int task = blockIdx.x * 2 + g;         // grid exact: 7688*2 = 15376
    const int b  = task / LPB;
    const int l  = task - b * LPB;
    const int ph = l / 31, pw = l - ph * 31;
    const float* xb = x + (size_t)(b * 3) * 262144 + (ph * 16) * 512 + pw * 16;
    float* S = sS[g];
    float gsum = 0.0f;
    __syncthreads();

    for (int c = 0; c < 3; ++c) {
        // pass 1: U[r][j] = sum_k P[r][k] D[j][k]; lane = r, row load contiguous
        const float4* row = (const float4*)(xb + c * 262144 + lane * 512);
        float p[32];
        #pragma unroll
        for (int q = 0; q < 8; ++q) {
            float4 f = row[q];
            p[4*q] = f.x; p[4*q+1] = f.y; p[4*q+2] = f.z; p[4*q+3] = f.w;
        }
        dct32(p, [&](int j, float acc) { S[j * 33 + lane] = acc; });
        __syncthreads();                         // wave_barrier (free)

        // pass 2: Z[i][c'] = sum_j D[i][j] U[j][c']; lane = c' (column of U)
        float u[32];
        #pragma unroll
        for (int j = 0; j < 32; ++j) u[j] = S[lane * 33 + j];   // TRANSPOSED read
        __syncthreads();                         // reads drained before next writes
        dct32(u, [&](int i, float z) {
            float lx = __logf(fabsf(z) + 1.0f);
            gsum = fmaf(lx, sF[i + lane], gsum); // s = row + col
        });
    }
    #pragma unroll
    for (int off = 16; off > 0; off >>= 1) gsum += __shfl_down(gsum, off, 32);
    if (lane == 0) partial[task] = gsum;
}

// ---------------- kernel 2: top-2 / bottom-2 per batch ----------------
// key = (grade_bits << 32) | idx ; grades >= 0 so float bits are monotone.
__global__ __launch_bounds__(256) void k_select(const float* __restrict__ partial,
                                                int* __restrict__ sel) {
    __shared__ unsigned long long smx1[256], smx2[256], smn1[256], smn2[256];
    const int b = blockIdx.x, tid = threadIdx.x;
    unsigned long long mx1 = 0, mx2 = 0, mn1 = ~0ULL, mn2 = ~0ULL;
    for (int l = tid; l < LPB; l += 256) {
        unsigned int bits = __float_as_uint(partial[b * LPB + l]);
        unsigned long long k = ((unsigned long long)bits << 32) | (unsigned int)l;
        if (k > mx1) { mx2 = mx1; mx1 = k; } else if (k > mx2) { mx2 = k; }
        if (k < mn1) { mn2 = mn1; mn1 = k; } else if (k < mn2) { mn2 = k; }
    }
    smx1[tid] = mx1; smx2[tid] = mx2; smn1[tid] = mn1; smn2[tid] = mn2;
    for (int off = 128; off > 0; off >>= 1) {
        __syncthreads();
        if (tid < off) {
            unsigned long long a1 = smx1[tid], a2 = smx2[tid], b1 = smx1[tid + off], b2 = smx2[tid + off];
            unsigned long long lo = a1 < b1 ? a1 : b1, hi = a1 < b1 ? b1 : a1;
            unsigned long long c2 = a2 > b2 ? a2 : b2;
            smx1[tid] = hi; smx2[tid] = lo > c2 ? lo : c2;
            a1 = smn1[tid]; a2 = smn2[tid]; b1 = smn1[tid + off]; b2 = smn2[tid + off];
            lo = a1 < b1 ? a1 : b1; hi = a1 < b1 ? b1 : a1;
            c2 = a2 < b2 ? a2 : b2;
            smn1[tid] = lo; smn2[tid] = hi < c2 ? hi : c2;
        }
    }
    __syncthreads();
    if (tid == 0) {
        sel[b * 4 + 0] = (int)(smn1[0] & 0xffffffffu);  // x_minmin
        sel[b * 4 + 1] = (int)(smx1[0] & 0xffffffffu);  // x_maxmax
        sel[b * 4 + 2] = (int)(smn2[0] & 0xffffffffu);  // x_minmin1
        sel[b * 4 + 3] = (int)(smx2[0] & 0xffffffffu);  // x_maxmax1
    }
}

// ---------------- kernel 3: gather selected raw patches ----------------
// level_y == patches exactly (LEVEL_FILT all-ones, D orthonormal).
__global__ __launch_bounds__(256) void k_gather(const float* __restrict__ x,
                                                const int* __restrict__ sel,
                                                float* __restrict__ out) {
    const int e = blockIdx.x * 256 + threadIdx.x;    // 768*256 = 196608 exact
    const int o  = e / 49152;
    const int r  = e - o * 49152;
    const int b  = r / 3072;
    const int r2 = r - b * 3072;
    const int c  = r2 >> 10;
    const int p  = r2 & 1023;
    const int i  = p >> 5, j = p & 31;
    const int l  = sel[b * 4 + o];
    const int r0 = (l / 31) * 16, c0 = (l - (l / 31) * 31) * 16;
    out[e] = x[((b * 3 + c) * 512 + r0 + i) * 512 + c0 + j];
}

extern "C" void kernel_launch(void* const* d_in, const int* in_sizes, int n_in,
                              void* d_out, int out_size, void* d_ws, size_t ws_size,
                              hipStream_t stream) {
    const float* x = (const float*)d_in[0];
    float* out     = (float*)d_out;
    float* partial = (float*)d_ws;                   // NP floats
    int*   sel     = (int*)d_ws + 16384;             // 64 ints at byte offset 64 KiB
    k_grade <<<NP / 2, 64, 0, stream>>>(x, partial);
    k_select<<<16,     256, 0, stream>>>(partial, sel);
    k_gather<<<768,    256, 0, stream>>>(x, sel, out);
}

// Round 4
// 122.650 us; speedup vs baseline: 1.7846x; 1.4617x over previous
//
#include <hip/hip_runtime.h>
#include <cstdint>

// ---------------- compile-time DCT tables (butterfly-packed) ----------------
// __device__ constexpr (NOT __constant__): initializer is compiler-visible, so
// compile-time-indexed reads fold to 32-bit literals in v_fmac_f32 — no s_load.
constexpr double kPI = 3.14159265358979323846264338327950288;
constexpr double cos_poly(double x) {            // |x| <= pi/2, Taylor
    double x2 = x * x, term = 1.0, sum = 1.0;
    for (int n = 1; n <= 13; ++n) { term *= -x2 / double((2 * n - 1) * (2 * n)); sum += term; }
    return sum;
}
constexpr double cos_idx(int a) {                // cos(a*pi/64), a mod 128
    a &= 127;
    if (a <= 32)  return  cos_poly(a * kPI / 64.0);
    if (a <= 64)  return -cos_poly((64 - a) * kPI / 64.0);
    if (a <= 96)  return -cos_poly((a - 64) * kPI / 64.0);
    return cos_poly((128 - a) * kPI / 64.0);
}
constexpr double csqrt(double v) {
    double x = 1.0;
    for (int i = 0; i < 60; ++i) x = 0.5 * (x + v / x);
    return x;
}
constexpr float Dij(int i, int j) {              // D[i][j], 32-point DCT-II
    double sc = (i == 0) ? csqrt(1.0 / 32.0) : 0.25;   // sqrt(2/32) == 0.25 exactly
    int a = ((2 * j + 1) * i) & 127;
    return (float)(sc * cos_idx(a));
}
// D[i][31-k] = (-1)^i D[i][k]  (stage 1);  even rows fold again (stage 2).
struct OddT { float d[256]; };                   // Odd[m][k] = D[2m+1][k], k<16
constexpr OddT make_odd() { OddT t{}; for (int m = 0; m < 16; ++m) for (int k = 0; k < 16; ++k) t.d[m*16+k] = Dij(2*m+1, k); return t; }
struct E8T { float d[64]; };
constexpr E8T make_e0() { E8T t{}; for (int m = 0; m < 8; ++m) for (int k = 0; k < 8; ++k) t.d[m*8+k] = Dij(4*m,   k); return t; }
constexpr E8T make_e2() { E8T t{}; for (int m = 0; m < 8; ++m) for (int k = 0; k < 8; ++k) t.d[m*8+k] = Dij(4*m+2, k); return t; }
struct FTab { float f[64]; };
constexpr FTab make_F() {                        // f(s) = sum_g [s in band g] 2^g/n_g
    FTab t{};
    const int lo[6] = {0, 11, 22, 32, 43, 54};
    const int hi[6] = {10, 21, 32, 42, 53, 62};  // s=32 in bands 2 AND 3 (fp64 boundary = 32.0)
    const int n [6] = {66, 187, 306, 286, 165, 45};
    for (int s = 0; s < 64; ++s) {
        double acc = 0.0, w = 1.0;
        for (int g = 0; g < 6; ++g) { if (s >= lo[g] && s <= hi[g]) acc += w / double(n[g]); w *= 2.0; }
        t.f[s] = (float)acc;
    }
    return t;
}
__device__ constexpr OddT cOdd = make_odd();
__device__ constexpr E8T  cE0  = make_e0();
__device__ constexpr E8T  cE2  = make_e2();
__device__ constexpr FTab cF   = make_F();

#define NP  15376   // 16 * 961 patches
#define LPB 961     // 31*31 patches per batch image

// 32-point DCT-II with 2 butterfly stages: 384 FMA + 48 add (vs 1024 FMA).
// All coefficients are compile-time constants -> inline literals.
template <typename EMIT>
__device__ __forceinline__ void dct32(const float* __restrict__ v, EMIT&& emit) {
    float e[16], o[16];
    #pragma unroll
    for (int k = 0; k < 16; ++k) { e[k] = v[k] + v[31-k]; o[k] = v[k] - v[31-k]; }
    float ee[8], eo[8];
    #pragma unroll
    for (int k = 0; k < 8; ++k)  { ee[k] = e[k] + e[15-k]; eo[k] = e[k] - e[15-k]; }
    #pragma unroll
    for (int m = 0; m < 16; m += 2) {            // odd outputs, 2 chains for ILP
        float a = 0.f, b = 0.f;
        #pragma unroll
        for (int k = 0; k < 16; ++k) {
            a = fmaf(cOdd.d[m*16+k],     o[k], a);
            b = fmaf(cOdd.d[(m+1)*16+k], o[k], b);
        }
        emit(2*m+1, a); emit(2*m+3, b);
    }
    #pragma unroll
    for (int m = 0; m < 8; m += 2) {             // even outputs, 4 chains
        float a0 = 0.f, a2 = 0.f, b0 = 0.f, b2 = 0.f;
        #pragma unroll
        for (int k = 0; k < 8; ++k) {
            a0 = fmaf(cE0.d[m*8+k],     ee[k], a0);
            a2 = fmaf(cE2.d[m*8+k],     eo[k], a2);
            b0 = fmaf(cE0.d[(m+1)*8+k], ee[k], b0);
            b2 = fmaf(cE2.d[(m+1)*8+k], eo[k], b2);
        }
        emit(4*m, a0); emit(4*m+2, a2); emit(4*m+4, b0); emit(4*m+6, b2);
    }
}

// ---------------- kernel 1: per-patch grade ----------------
// 64-thread (single-wave) blocks.  Lane = row for pass 1 (contiguous float4
// row loads), 33-stride LDS transpose, lane = column for pass 2.
// LDS map: S[a*33 + b] = U[b][a]  (write S[j*33+lane]; read S[lane*33+j]).
__global__ __launch_bounds__(64) void k_grade(const float* __restrict__ x,
                                              float* __restrict__ partial) {
    __shared__ float sS[2][32 * 33];             // U buffer per 32-lane group
    __shared__ float sF[64];
    const int tid = threadIdx.x, g = tid >> 5, lane = tid & 31;
    sF[tid] = cF.f[tid];

    const int task = blockIdx.x * 2 + g;         // grid exact: 7688*2 = 15376
    const int b  = task / LPB;
    const int l  = task - b * LPB;
    const int ph = l / 31, pw = l - ph * 31;
    const float* xb = x + (size_t)(b * 3) * 262144 + (ph * 16) * 512 + pw * 16;
    float* S = sS[g];
    float gsum = 0.0f;
    __syncthreads();                             // sF visible (wave-level: cheap)

    float w[32];                                 // grade weights, once per patch
    #pragma unroll
    for (int i = 0; i < 32; ++i) w[i] = sF[lane + i];

    #pragma unroll 1                             // keep body rolled: I-cache
    for (int c = 0; c < 3; ++c) {
        // pass 1: U[r][j] = sum_k P[r][k] D[j][k]; lane = r, row load contiguous
        const float4* row = (const float4*)(xb + c * 262144 + lane * 512);
        float p[32];
        #pragma unroll
        for (int q = 0; q < 8; ++q) {
            float4 f = row[q];
            p[4*q] = f.x; p[4*q+1] = f.y; p[4*q+2] = f.z; p[4*q+3] = f.w;
        }
        dct32(p, [&](int j, float acc) { S[j * 33 + lane] = acc; });
        __syncthreads();

        // pass 2: Z[i][c'] = sum_j D[i][j] U[j][c']; lane = c' (column of U)
        float u[32];
        #pragma unroll
        for (int j = 0; j < 32; ++j) u[j] = S[lane * 33 + j];   // transposed read
        __syncthreads();                         // reads drained before next writes
        dct32(u, [&](int i, float z) {
            float lx = __logf(fabsf(z) + 1.0f);
            gsum = fmaf(lx, w[i], gsum);         // s = row + col, w in registers
        });
    }
    #pragma unroll
    for (int off = 16; off > 0; off >>= 1) gsum += __shfl_down(gsum, off, 32);
    if (lane == 0) partial[task] = gsum;
}

// ---------------- kernel 2: fused select + gather ----------------
// Block b: top-2/bottom-2 over its 961 grades (u64 key = grade_bits<<32 | idx
// matches stable-argsort tie semantics), then copies the 4 selected raw
// patches (level_y == patches: LEVEL_FILT all-ones, D orthonormal).
__global__ __launch_bounds__(256) void k_selgather(const float* __restrict__ partial,
                                                   const float* __restrict__ x,
                                                   float* __restrict__ out) {
    __shared__ unsigned long long smx1[256], smx2[256], smn1[256], smn2[256];
    __shared__ int ssel[4];
    const int b = blockIdx.x, tid = threadIdx.x;
    unsigned long long mx1 = 0, mx2 = 0, mn1 = ~0ULL, mn2 = ~0ULL;
    for (int l = tid; l < LPB; l += 256) {
        unsigned int bits = __float_as_uint(partial[b * LPB + l]);
        unsigned long long k = ((unsigned long long)bits << 32) | (unsigned int)l;
        if (k > mx1) { mx2 = mx1; mx1 = k; } else if (k > mx2) { mx2 = k; }
        if (k < mn1) { mn2 = mn1; mn1 = k; } else if (k < mn2) { mn2 = k; }
    }
    smx1[tid] = mx1; smx2[tid] = mx2; smn1[tid] = mn1; smn2[tid] = mn2;
    for (int off = 128; off > 0; off >>= 1) {
        __syncthreads();
        if (tid < off) {
            unsigned long long a1 = smx1[tid], a2 = smx2[tid], b1 = smx1[tid + off], b2 = smx2[tid + off];
            unsigned long long lo = a1 < b1 ? a1 : b1, hi = a1 < b1 ? b1 : a1;
            unsigned long long c2 = a2 > b2 ? a2 : b2;
            smx1[tid] = hi; smx2[tid] = lo > c2 ? lo : c2;
            a1 = smn1[tid]; a2 = smn2[tid]; b1 = smn1[tid + off]; b2 = smn2[tid + off];
            lo = a1 < b1 ? a1 : b1; hi = a1 < b1 ? b1 : a1;
            c2 = a2 < b2 ? a2 : b2;
            smn1[tid] = lo; smn2[tid] = hi < c2 ? hi : c2;
        }
    }
    __syncthreads();
    if (tid == 0) {
        ssel[0] = (int)(smn1[0] & 0xffffffffu);  // x_minmin
        ssel[1] = (int)(smx1[0] & 0xffffffffu);  // x_maxmax
        ssel[2] = (int)(smn2[0] & 0xffffffffu);  // x_minmin1
        ssel[3] = (int)(smx2[0] & 0xffffffffu);  // x_maxmax1
    }
    __syncthreads();

    // gather: 4 outputs x 3 ch x 32 x 32 floats = 3072 float4 per batch
    #pragma unroll
    for (int it = 0; it < 12; ++it) {
        const int q  = it * 256 + tid;           // [0, 3072)
        const int o  = q / 768;
        const int r2 = q - o * 768;
        const int c  = r2 >> 8;
        const int p  = r2 & 255;
        const int i  = p >> 3, j4 = p & 7;
        const int l  = ssel[o];
        const int r0 = (l / 31) * 16, c0 = (l - (l / 31) * 31) * 16;
        const float4 v = *(const float4*)(x + ((size_t)(b * 3 + c) * 512 + r0 + i) * 512 + c0 + 4 * j4);
        *(float4*)(out + (size_t)o * 49152 + b * 3072 + c * 1024 + i * 32 + 4 * j4) = v;
    }
}

extern "C" void kernel_launch(void* const* d_in, const int* in_sizes, int n_in,
                              void* d_out, int out_size, void* d_ws, size_t ws_size,
                              hipStream_t stream) {
    const float* x = (const float*)d_in[0];
    float* out     = (float*)d_out;
    float* partial = (float*)d_ws;               // NP floats
    k_grade    <<<NP / 2, 64,  0, stream>>>(x, partial);
    k_selgather<<<16,     256, 0, stream>>>(partial, x, out);
}

// Round 5
// 112.000 us; speedup vs baseline: 1.9543x; 1.0951x over previous
//
#include <hip/hip_runtime.h>
#include <cstdint>

// ---------------- compile-time DCT tables (butterfly-packed) ----------------
// __device__ constexpr: initializers are compiler-visible, every coefficient
// folds to a 32-bit literal operand on v_fmac_f32 — zero s_loads at runtime.
constexpr double kPI  = 3.14159265358979323846264338327950288;
constexpr double kLN2 = 0.69314718055994530941723212145818;
constexpr double cos_poly(double x) {            // |x| <= pi/2, Taylor
    double x2 = x * x, term = 1.0, sum = 1.0;
    for (int n = 1; n <= 13; ++n) { term *= -x2 / double((2 * n - 1) * (2 * n)); sum += term; }
    return sum;
}
constexpr double cos_idx(int a) {                // cos(a*pi/64), a mod 128
    a &= 127;
    if (a <= 32)  return  cos_poly(a * kPI / 64.0);
    if (a <= 64)  return -cos_poly((64 - a) * kPI / 64.0);
    if (a <= 96)  return -cos_poly((a - 64) * kPI / 64.0);
    return cos_poly((128 - a) * kPI / 64.0);
}
constexpr double csqrt(double v) {
    double x = 1.0;
    for (int i = 0; i < 60; ++i) x = 0.5 * (x + v / x);
    return x;
}
constexpr float Dij(int i, int j) {              // D[i][j], 32-point DCT-II
    double sc = (i == 0) ? csqrt(1.0 / 32.0) : 0.25;   // sqrt(2/32) == 0.25 exactly
    int a = ((2 * j + 1) * i) & 127;
    return (float)(sc * cos_idx(a));
}
// Fold identities (all exact for DCT-II):
//   D32[i][31-k]   = (-1)^i D32[i][k]        -> e/o split
//   D32[2m][15-k]  = (-1)^m D32[2m][k]       -> ee/eo split
//   D32[4m][7-k]   = (-1)^m D32[4m][k]       -> eee/eeo split
struct OddT { float d[256]; };                   // rows 2m+1 on o[16]
constexpr OddT make_odd() { OddT t{}; for (int m = 0; m < 16; ++m) for (int k = 0; k < 16; ++k) t.d[m*16+k] = Dij(2*m+1, k); return t; }
struct E8T { float d[64]; };                     // rows 4m+2 on eo[8]
constexpr E8T make_e2() { E8T t{}; for (int m = 0; m < 8; ++m) for (int k = 0; k < 8; ++k) t.d[m*8+k] = Dij(4*m+2, k); return t; }
struct E4T { float d[16]; };
constexpr E4T make_ee() { E4T t{}; for (int m = 0; m < 4; ++m) for (int k = 0; k < 4; ++k) t.d[m*4+k] = Dij(8*m,   k); return t; }   // rows 8t on eee[4]
constexpr E4T make_eo() { E4T t{}; for (int m = 0; m < 4; ++m) for (int k = 0; k < 4; ++k) t.d[m*4+k] = Dij(8*m+4, k); return t; }   // rows 8t+4 on eeo[4]
struct FTab { float f[64]; };
constexpr FTab make_F() {                        // f(s) = ln2 * sum_g [s in band g] 2^g/n_g
    FTab t{};                                    // (ln2 folded in: we use log2 instead of ln)
    const int lo[6] = {0, 11, 22, 32, 43, 54};
    const int hi[6] = {10, 21, 32, 42, 53, 62};  // s=32 in bands 2 AND 3 (fp64 boundary = 32.0)
    const int n [6] = {66, 187, 306, 286, 165, 45};
    for (int s = 0; s < 64; ++s) {
        double acc = 0.0, w = 1.0;
        for (int g = 0; g < 6; ++g) { if (s >= lo[g] && s <= hi[g]) acc += w / double(n[g]); w *= 2.0; }
        t.f[s] = (float)(acc * kLN2);
    }
    return t;
}
__device__ constexpr OddT cOdd = make_odd();
__device__ constexpr E8T  cE2  = make_e2();
__device__ constexpr E4T  cEE  = make_ee();
__device__ constexpr E4T  cEO  = make_eo();
__device__ constexpr FTab cF   = make_F();

#define NP  15376   // 16 * 961 patches
#define LPB 961     // 31*31 patches per batch image
#define SST 36      // LDS transpose stride: 16B-aligned rows (36*4=144), banks 4j+lane -> conflict-free

// 32-point DCT-II, 3 butterfly stages: 352 FMA + 56 add (vs 1024 FMA dense).
template <typename EMIT>
__device__ __forceinline__ void dct32(const float* __restrict__ v, EMIT&& emit) {
    float e[16], o[16];
    #pragma unroll
    for (int k = 0; k < 16; ++k) { e[k] = v[k] + v[31-k]; o[k] = v[k] - v[31-k]; }
    float ee[8], eo[8];
    #pragma unroll
    for (int k = 0; k < 8; ++k)  { ee[k] = e[k] + e[15-k]; eo[k] = e[k] - e[15-k]; }
    float eee[4], eeo[4];
    #pragma unroll
    for (int k = 0; k < 4; ++k)  { eee[k] = ee[k] + ee[7-k]; eeo[k] = ee[k] - ee[7-k]; }
    #pragma unroll
    for (int m = 0; m < 16; m += 2) {            // odd rows 2m+1: 2 chains
        float a = 0.f, b = 0.f;
        #pragma unroll
        for (int k = 0; k < 16; ++k) {
            a = fmaf(cOdd.d[m*16+k],     o[k], a);
            b = fmaf(cOdd.d[(m+1)*16+k], o[k], b);
        }
        emit(2*m+1, a); emit(2*m+3, b);
    }
    #pragma unroll
    for (int m = 0; m < 8; m += 2) {             // rows 4m+2: 2 chains
        float a = 0.f, b = 0.f;
        #pragma unroll
        for (int k = 0; k < 8; ++k) {
            a = fmaf(cE2.d[m*8+k],     eo[k], a);
            b = fmaf(cE2.d[(m+1)*8+k], eo[k], b);
        }
        emit(4*m+2, a); emit(4*m+6, b);
    }
    {                                            // rows 8t / 8t+4: 8 chains of 4 FMA
        float a0=0.f,a1=0.f,a2=0.f,a3=0.f,b0=0.f,b1=0.f,b2=0.f,b3=0.f;
        #pragma unroll
        for (int k = 0; k < 4; ++k) {
            a0 = fmaf(cEE.d[0*4+k], eee[k], a0);
            a1 = fmaf(cEE.d[1*4+k], eee[k], a1);
            a2 = fmaf(cEE.d[2*4+k], eee[k], a2);
            a3 = fmaf(cEE.d[3*4+k], eee[k], a3);
            b0 = fmaf(cEO.d[0*4+k], eeo[k], b0);
            b1 = fmaf(cEO.d[1*4+k], eeo[k], b1);
            b2 = fmaf(cEO.d[2*4+k], eeo[k], b2);
            b3 = fmaf(cEO.d[3*4+k], eeo[k], b3);
        }
        emit(0, a0); emit(8, a1); emit(16, a2); emit(24, a3);
        emit(4, b0); emit(12, b1); emit(20, b2); emit(28, b3);
    }
}

// ---------------- kernel 1: per-patch grade ----------------
// 128-thread blocks = 4 patch-groups (2 waves): more waves/CU than 64-thread.
// Lane = row for pass 1 (contiguous float4 row loads, next channel
// prefetched during compute), stride-36 LDS transpose (b128-aligned reads),
// lane = column for pass 2.  S[a*SST+b] = U[b][a].
__global__ __launch_bounds__(128) void k_grade(const float* __restrict__ x,
                                               float* __restrict__ partial) {
    __shared__ __align__(16) float sS[4][32 * SST];
    __shared__ float sF[64];
    const int tid = threadIdx.x, g = tid >> 5, lane = tid & 31;
    if (tid < 64) sF[tid] = cF.f[tid];

    const int task = blockIdx.x * 4 + g;         // grid exact: 3844*4 = 15376
    const int b  = task / LPB;
    const int l  = task - b * LPB;
    const int ph = l / 31, pw = l - ph * 31;
    const float* cb = x + (size_t)(b * 3) * 262144 + (ph * 16) * 512 + pw * 16 + lane * 512;
    float* S = sS[g];
    __syncthreads();                             // sF visible

    float w[32];                                 // grade weights (ln2-scaled), once per patch
    #pragma unroll
    for (int i = 0; i < 32; ++i) w[i] = sF[lane + i];

    float4 cur[8];                               // software pipeline: channel c+1 in flight
    #pragma unroll
    for (int q = 0; q < 8; ++q) cur[q] = ((const float4*)cb)[q];

    float gsum = 0.0f;
    #pragma unroll 1                             // rolled: keep literal-heavy body I-cache-sized
    for (int c = 0; c < 3; ++c) {
        float p[32];
        #pragma unroll
        for (int q = 0; q < 8; ++q) {
            float4 f = cur[q];
            p[4*q] = f.x; p[4*q+1] = f.y; p[4*q+2] = f.z; p[4*q+3] = f.w;
        }
        if (c < 2) {                             // prefetch next channel behind dct
            cb += 262144;
            #pragma unroll
            for (int q = 0; q < 8; ++q) cur[q] = ((const float4*)cb)[q];
        }
        // pass 1: U[r][j] = sum_k P[r][k] D[j][k]; lane = r
        dct32(p, [&](int j, float acc) { S[j * SST + lane] = acc; });
        __syncthreads();

        // pass 2: lane = column; transposed read as 8 x ds_read_b128
        float u[32];
        #pragma unroll
        for (int q = 0; q < 8; ++q) {
            float4 uu = *(const float4*)&S[lane * SST + 4 * q];
            u[4*q] = uu.x; u[4*q+1] = uu.y; u[4*q+2] = uu.z; u[4*q+3] = uu.w;
        }
        __syncthreads();                         // reads drained before next writes
        dct32(u, [&](int i, float z) {
            gsum = fmaf(__log2f(fabsf(z) + 1.0f), w[i], gsum);  // ln2 folded into w
        });
    }
    #pragma unroll
    for (int off = 16; off > 0; off >>= 1) gsum += __shfl_down(gsum, off, 32);
    if (lane == 0) partial[task] = gsum;
}

// ---------------- kernel 2: fused select + gather ----------------
// Block b: top-2/bottom-2 over its 961 grades (u64 key = grade_bits<<32 | idx
// matches stable-argsort tie semantics), then copies the 4 selected raw
// patches (level_y == patches: LEVEL_FILT all-ones, D orthonormal).
__global__ __launch_bounds__(256) void k_selgather(const float* __restrict__ partial,
                                                   const float* __restrict__ x,
                                                   float* __restrict__ out) {
    __shared__ unsigned long long smx1[256], smx2[256], smn1[256], smn2[256];
    __shared__ int ssel[4];
    const int b = blockIdx.x, tid = threadIdx.x;
    unsigned long long mx1 = 0, mx2 = 0, mn1 = ~0ULL, mn2 = ~0ULL;
    for (int l = tid; l < LPB; l += 256) {
        unsigned int bits = __float_as_uint(partial[b * LPB + l]);
        unsigned long long k = ((unsigned long long)bits << 32) | (unsigned int)l;
        if (k > mx1) { mx2 = mx1; mx1 = k; } else if (k > mx2) { mx2 = k; }
        if (k < mn1) { mn2 = mn1; mn1 = k; } else if (k < mn2) { mn2 = k; }
    }
    smx1[tid] = mx1; smx2[tid] = mx2; smn1[tid] = mn1; smn2[tid] = mn2;
    for (int off = 128; off > 0; off >>= 1) {
        __syncthreads();
        if (tid < off) {
            unsigned long long a1 = smx1[tid], a2 = smx2[tid], b1 = smx1[tid + off], b2 = smx2[tid + off];
            unsigned long long lo = a1 < b1 ? a1 : b1, hi = a1 < b1 ? b1 : a1;
            unsigned long long c2 = a2 > b2 ? a2 : b2;
            smx1[tid] = hi; smx2[tid] = lo > c2 ? lo : c2;
            a1 = smn1[tid]; a2 = smn2[tid]; b1 = smn1[tid + off]; b2 = smn2[tid + off];
            lo = a1 < b1 ? a1 : b1; hi = a1 < b1 ? b1 : a1;
            c2 = a2 < b2 ? a2 : b2;
            smn1[tid] = lo; smn2[tid] = hi < c2 ? hi : c2;
        }
    }
    __syncthreads();
    if (tid == 0) {
        ssel[0] = (int)(smn1[0] & 0xffffffffu);  // x_minmin
        ssel[1] = (int)(smx1[0] & 0xffffffffu);  // x_maxmax
        ssel[2] = (int)(smn2[0] & 0xffffffffu);  // x_minmin1
        ssel[3] = (int)(smx2[0] & 0xffffffffu);  // x_maxmax1
    }
    __syncthreads();

    // gather: 4 outputs x 3 ch x 32 x 32 floats = 3072 float4 per batch
    #pragma unroll
    for (int it = 0; it < 12; ++it) {
        const int q  = it * 256 + tid;           // [0, 3072)
        const int o  = q / 768;
        const int r2 = q - o * 768;
        const int c  = r2 >> 8;
        const int p  = r2 & 255;
        const int i  = p >> 3, j4 = p & 7;
        const int l  = ssel[o];
        const int r0 = (l / 31) * 16, c0 = (l - (l / 31) * 31) * 16;
        const float4 v = *(const float4*)(x + ((size_t)(b * 3 + c) * 512 + r0 + i) * 512 + c0 + 4 * j4);
        *(float4*)(out + (size_t)o * 49152 + b * 3072 + c * 1024 + i * 32 + 4 * j4) = v;
    }
}

extern "C" void kernel_launch(void* const* d_in, const int* in_sizes, int n_in,
                              void* d_out, int out_size, void* d_ws, size_t ws_size,
                              hipStream_t stream) {
    const float* x = (const float*)d_in[0];
    float* out     = (float*)d_out;
    float* partial = (float*)d_ws;               // NP floats
    k_grade    <<<NP / 4, 128, 0, stream>>>(x, partial);
    k_selgather<<<16,     256, 0, stream>>>(partial, x, out);
}

// Round 6
// 111.295 us; speedup vs baseline: 1.9667x; 1.0063x over previous
//
#include <hip/hip_runtime.h>
#include <cstdint>

// ---------------- compile-time DCT tables (butterfly-packed) ----------------
// __device__ constexpr: initializers are compiler-visible, every coefficient
// folds to a 32-bit literal operand on v_fmac_f32 — zero s_loads at runtime.
constexpr double kPI  = 3.14159265358979323846264338327950288;
constexpr double kLN2 = 0.69314718055994530941723212145818;
constexpr double cos_poly(double x) {            // |x| <= pi/2, Taylor
    double x2 = x * x, term = 1.0, sum = 1.0;
    for (int n = 1; n <= 13; ++n) { term *= -x2 / double((2 * n - 1) * (2 * n)); sum += term; }
    return sum;
}
constexpr double cos_idx(int a) {                // cos(a*pi/64), a mod 128
    a &= 127;
    if (a <= 32)  return  cos_poly(a * kPI / 64.0);
    if (a <= 64)  return -cos_poly((64 - a) * kPI / 64.0);
    if (a <= 96)  return -cos_poly((a - 64) * kPI / 64.0);
    return cos_poly((128 - a) * kPI / 64.0);
}
constexpr double csqrt(double v) {
    double x = 1.0;
    for (int i = 0; i < 60; ++i) x = 0.5 * (x + v / x);
    return x;
}
constexpr float Dij(int i, int j) {              // D[i][j], 32-point DCT-II
    double sc = (i == 0) ? csqrt(1.0 / 32.0) : 0.25;   // sqrt(2/32) == 0.25 exactly
    int a = ((2 * j + 1) * i) & 127;
    return (float)(sc * cos_idx(a));
}
// Fold identities (all exact for DCT-II):
//   D32[i][31-k]   = (-1)^i D32[i][k]        -> e/o split
//   D32[2m][15-k]  = (-1)^m D32[2m][k]       -> ee/eo split
//   D32[4m][7-k]   = (-1)^m D32[4m][k]       -> eee/eeo split
struct OddT { float d[256]; };                   // rows 2m+1 on o[16]
constexpr OddT make_odd() { OddT t{}; for (int m = 0; m < 16; ++m) for (int k = 0; k < 16; ++k) t.d[m*16+k] = Dij(2*m+1, k); return t; }
struct E8T { float d[64]; };                     // rows 4m+2 on eo[8]
constexpr E8T make_e2() { E8T t{}; for (int m = 0; m < 8; ++m) for (int k = 0; k < 8; ++k) t.d[m*8+k] = Dij(4*m+2, k); return t; }
struct E4T { float d[16]; };
constexpr E4T make_ee() { E4T t{}; for (int m = 0; m < 4; ++m) for (int k = 0; k < 4; ++k) t.d[m*4+k] = Dij(8*m,   k); return t; }   // rows 8t on eee[4]
constexpr E4T make_eo() { E4T t{}; for (int m = 0; m < 4; ++m) for (int k = 0; k < 4; ++k) t.d[m*4+k] = Dij(8*m+4, k); return t; }   // rows 8t+4 on eeo[4]
struct FTab { float f[64]; };
constexpr FTab make_F() {                        // f(s) = ln2 * sum_g [s in band g] 2^g/n_g
    FTab t{};                                    // (ln2 folded in: we use log2 instead of ln)
    const int lo[6] = {0, 11, 22, 32, 43, 54};
    const int hi[6] = {10, 21, 32, 42, 53, 62};  // s=32 in bands 2 AND 3 (fp64 boundary = 32.0)
    const int n [6] = {66, 187, 306, 286, 165, 45};
    for (int s = 0; s < 64; ++s) {
        double acc = 0.0, w = 1.0;
        for (int g = 0; g < 6; ++g) { if (s >= lo[g] && s <= hi[g]) acc += w / double(n[g]); w *= 2.0; }
        t.f[s] = (float)(acc * kLN2);
    }
    return t;
}
__device__ constexpr OddT cOdd = make_odd();
__device__ constexpr E8T  cE2  = make_e2();
__device__ constexpr E4T  cEE  = make_ee();
__device__ constexpr E4T  cEO  = make_eo();
__device__ constexpr FTab cF   = make_F();

#define NP  15376   // 16 * 961 patches
#define NPC 46128   // NP * 3 (patch, channel) tasks
#define LPB 961     // 31*31 patches per batch image
#define SST 34      // LDS stride: write bank=(2j+lane) c-free; b64 read bank=2(lane+h),
                    // only lanes l/l+16 alias (2-way = free, m136); 8B-aligned (136|8)

// 32-point DCT-II, 3 butterfly stages: 352 FMA + 56 add (vs 1024 FMA dense).
template <typename EMIT>
__device__ __forceinline__ void dct32(const float* __restrict__ v, EMIT&& emit) {
    float e[16], o[16];
    #pragma unroll
    for (int k = 0; k < 16; ++k) { e[k] = v[k] + v[31-k]; o[k] = v[k] - v[31-k]; }
    float ee[8], eo[8];
    #pragma unroll
    for (int k = 0; k < 8; ++k)  { ee[k] = e[k] + e[15-k]; eo[k] = e[k] - e[15-k]; }
    float eee[4], eeo[4];
    #pragma unroll
    for (int k = 0; k < 4; ++k)  { eee[k] = ee[k] + ee[7-k]; eeo[k] = ee[k] - ee[7-k]; }
    #pragma unroll
    for (int m = 0; m < 16; m += 2) {            // odd rows 2m+1: 2 chains
        float a = 0.f, b = 0.f;
        #pragma unroll
        for (int k = 0; k < 16; ++k) {
            a = fmaf(cOdd.d[m*16+k],     o[k], a);
            b = fmaf(cOdd.d[(m+1)*16+k], o[k], b);
        }
        emit(2*m+1, a); emit(2*m+3, b);
    }
    #pragma unroll
    for (int m = 0; m < 8; m += 2) {             // rows 4m+2: 2 chains
        float a = 0.f, b = 0.f;
        #pragma unroll
        for (int k = 0; k < 8; ++k) {
            a = fmaf(cE2.d[m*8+k],     eo[k], a);
            b = fmaf(cE2.d[(m+1)*8+k], eo[k], b);
        }
        emit(4*m+2, a); emit(4*m+6, b);
    }
    {                                            // rows 8t / 8t+4: 8 chains of 4 FMA
        float a0=0.f,a1=0.f,a2=0.f,a3=0.f,b0=0.f,b1=0.f,b2=0.f,b3=0.f;
        #pragma unroll
        for (int k = 0; k < 4; ++k) {
            a0 = fmaf(cEE.d[0*4+k], eee[k], a0);
            a1 = fmaf(cEE.d[1*4+k], eee[k], a1);
            a2 = fmaf(cEE.d[2*4+k], eee[k], a2);
            a3 = fmaf(cEE.d[3*4+k], eee[k], a3);
            b0 = fmaf(cEO.d[0*4+k], eeo[k], b0);
            b1 = fmaf(cEO.d[1*4+k], eeo[k], b1);
            b2 = fmaf(cEO.d[2*4+k], eeo[k], b2);
            b3 = fmaf(cEO.d[3*4+k], eeo[k], b3);
        }
        emit(0, a0); emit(8, a1); emit(16, a2); emit(24, a3);
        emit(4, b0); emit(12, b1); emit(20, b2); emit(28, b3);
    }
}

// ---------------- kernel 1: per-(patch,channel) grade partial ----------------
// One 32-lane group = one (patch, channel); 64-thread single-wave blocks
// (s_barrier lowers to waitcnt-only), one barrier per task, no register
// hoards -> high wave count (22/SIMD demand) hides all latency.
__global__ __launch_bounds__(64) void k_grade(const float* __restrict__ x,
                                              float* __restrict__ partial) {
    __shared__ __align__(16) float sS[2][32 * SST];
    __shared__ float sF[64];
    const int tid = threadIdx.x, g = tid >> 5, lane = tid & 31;
    sF[tid] = cF.f[tid];

    const int tc   = blockIdx.x * 2 + g;         // grid exact: 23064*2 = 46128
    const int task = tc / 3, c = tc - task * 3;
    const int b  = task / LPB;
    const int l  = task - b * LPB;
    const int ph = l / 31, pw = l - ph * 31;
    const float4* row = (const float4*)(x + (size_t)(b * 3 + c) * 262144
                                          + (ph * 16 + lane) * 512 + pw * 16);
    float* S = sS[g];

    // pass 1: U[r][j] = sum_k P[r][k] D[j][k]; lane = r, contiguous float4 row
    float p[32];
    #pragma unroll
    for (int q = 0; q < 8; ++q) {
        float4 f = row[q];
        p[4*q] = f.x; p[4*q+1] = f.y; p[4*q+2] = f.z; p[4*q+3] = f.w;
    }
    dct32(p, [&](int j, float acc) { S[j * SST + lane] = acc; });
    __syncthreads();                             // single-wave: waitcnt only

    // pass 2: lane = column of U; transposed read as 16 x ds_read_b64
    float u[32];
    #pragma unroll
    for (int h = 0; h < 16; ++h) {
        float2 uu = *(const float2*)&S[lane * SST + 2 * h];
        u[2*h] = uu.x; u[2*h+1] = uu.y;
    }
    float gsum = 0.0f;
    dct32(u, [&](int i, float z) {
        gsum = fmaf(__log2f(fabsf(z) + 1.0f), sF[i + lane], gsum);  // ln2 in sF
    });
    #pragma unroll
    for (int off = 16; off > 0; off >>= 1) gsum += __shfl_down(gsum, off, 32);
    if (lane == 0) partial[tc] = gsum;
}

// ---------------- kernel 2: fused select + gather ----------------
// Block b: sum 3 channel partials (deterministic order), top-2/bottom-2 via
// u64 key = grade_bits<<32 | idx (matches stable-argsort tie semantics), then
// copy the 4 selected raw patches (level_y == patches: LEVEL_FILT all-ones,
// D orthonormal).
__global__ __launch_bounds__(256) void k_selgather(const float* __restrict__ partial,
                                                   const float* __restrict__ x,
                                                   float* __restrict__ out) {
    __shared__ unsigned long long smx1[256], smx2[256], smn1[256], smn2[256];
    __shared__ int ssel[4];
    const int b = blockIdx.x, tid = threadIdx.x;
    unsigned long long mx1 = 0, mx2 = 0, mn1 = ~0ULL, mn2 = ~0ULL;
    for (int l = tid; l < LPB; l += 256) {
        const float* pp = partial + (size_t)(b * LPB + l) * 3;
        float gr = pp[0] + pp[1] + pp[2];
        unsigned int bits = __float_as_uint(gr);
        unsigned long long k = ((unsigned long long)bits << 32) | (unsigned int)l;
        if (k > mx1) { mx2 = mx1; mx1 = k; } else if (k > mx2) { mx2 = k; }
        if (k < mn1) { mn2 = mn1; mn1 = k; } else if (k < mn2) { mn2 = k; }
    }
    smx1[tid] = mx1; smx2[tid] = mx2; smn1[tid] = mn1; smn2[tid] = mn2;
    for (int off = 128; off > 0; off >>= 1) {
        __syncthreads();
        if (tid < off) {
            unsigned long long a1 = smx1[tid], a2 = smx2[tid], b1 = smx1[tid + off], b2 = smx2[tid + off];
            unsigned long long lo = a1 < b1 ? a1 : b1, hi = a1 < b1 ? b1 : a1;
            unsigned long long c2 = a2 > b2 ? a2 : b2;
            smx1[tid] = hi; smx2[tid] = lo > c2 ? lo : c2;
            a1 = smn1[tid]; a2 = smn2[tid]; b1 = smn1[tid + off]; b2 = smn2[tid + off];
            lo = a1 < b1 ? a1 : b1; hi = a1 < b1 ? b1 : a1;
            c2 = a2 < b2 ? a2 : b2;
            smn1[tid] = lo; smn2[tid] = hi < c2 ? hi : c2;
        }
    }
    __syncthreads();
    if (tid == 0) {
        ssel[0] = (int)(smn1[0] & 0xffffffffu);  // x_minmin
        ssel[1] = (int)(smx1[0] & 0xffffffffu);  // x_maxmax
        ssel[2] = (int)(smn2[0] & 0xffffffffu);  // x_minmin1
        ssel[3] = (int)(smx2[0] & 0xffffffffu);  // x_maxmax1
    }
    __syncthreads();

    // gather: 4 outputs x 3 ch x 32 x 32 floats = 3072 float4 per batch
    #pragma unroll
    for (int it = 0; it < 12; ++it) {
        const int q  = it * 256 + tid;           // [0, 3072)
        const int o  = q / 768;
        const int r2 = q - o * 768;
        const int c  = r2 >> 8;
        const int p  = r2 & 255;
        const int i  = p >> 3, j4 = p & 7;
        const int l  = ssel[o];
        const int r0 = (l / 31) * 16, c0 = (l - (l / 31) * 31) * 16;
        const float4 v = *(const float4*)(x + ((size_t)(b * 3 + c) * 512 + r0 + i) * 512 + c0 + 4 * j4);
        *(float4*)(out + (size_t)o * 49152 + b * 3072 + c * 1024 + i * 32 + 4 * j4) = v;
    }
}

extern "C" void kernel_launch(void* const* d_in, const int* in_sizes, int n_in,
                              void* d_out, int out_size, void* d_ws, size_t ws_size,
                              hipStream_t stream) {
    const float* x = (const float*)d_in[0];
    float* out     = (float*)d_out;
    float* partial = (float*)d_ws;               // NPC floats (184 KB)
    k_grade    <<<NPC / 2, 64, 0, stream>>>(x, partial);
    k_selgather<<<16,     256, 0, stream>>>(partial, x, out);
}